// Round 5
// baseline (351.559 us; speedup 1.0000x reference)
//
#include <hip/hip_runtime.h>
#include <hip/hip_bf16.h>

typedef __bf16 bf16_t;
typedef __bf16 bf16x8 __attribute__((ext_vector_type(8)));
typedef float  f32x4  __attribute__((ext_vector_type(4)));
typedef unsigned int u32x4 __attribute__((ext_vector_type(4)));

#define DDIM 1024
#define NTOK 1024
#define MATN (1024 * 1024)
#define TM 64      // m-rows per m-tile (and per wave)
#define TNW 32     // n-cols per wave
// ws: wt 18,874,368 + xb 2,097,152 + G 8,388,608 + meta ~57 KB ~= 29.4 MiB (known good)

// ---------------- prep: zero counters, init pad slots, convert x->bf16 ----------------
__global__ void prep_k(const float* __restrict__ x, bf16_t* __restrict__ xb,
                       int* __restrict__ counts, int* __restrict__ list,
                       float* __restrict__ wrow) {
  const int i = blockIdx.x * 256 + threadIdx.x;  // grid 512 -> 131072 threads
  const int j = i * 8;
  const f32x4 a = *(const f32x4*)(x + j);
  const f32x4 b = *(const f32x4*)(x + j + 4);
  bf16x8 v;
#pragma unroll
  for (int t = 0; t < 4; ++t) { v[t] = (bf16_t)a[t]; v[t + 4] = (bf16_t)b[t]; }
  *(bf16x8*)(xb + j) = v;
  if (i < 16) counts[i] = 0;
  if (i < 4096) { list[i] = 0; wrow[i] = 0.f; }   // pad slots: token 0, weight 0
}

// ---------------- weight transpose+convert: fp32 src[k][n] -> bf16 dst[n][k] ----------------
// All-dword LDS ops: pack (k,k+1) bf16 pairs -> ds_write_b32 (stride-33 rows, <=2-way banks),
// read rows back as 8x b32, store 2x16B coalesced. Round-4 version used 16 sub-word DS ops.
__global__ void transpose_k(const float* __restrict__ src8, const float* __restrict__ srcS,
                            bf16_t* __restrict__ dst0) {
  const int e = blockIdx.z;
  const float* src = (e < 8) ? src8 + (size_t)e * MATN : srcS;
  bf16_t* dst = dst0 + (size_t)e * MATN;

  __shared__ unsigned int T[64][33];  // [n][k-pair], +1 dword pad
  const int t = threadIdx.x;          // 256
  const int k0 = blockIdx.y * 64, n0 = blockIdx.x * 64;
  {
    const int kp = t >> 3, cg = t & 7;   // kp: k-pair 0..31, cg: col-group 0..7
    const float* s0 = src + (size_t)(k0 + 2 * kp) * DDIM + n0 + cg * 8;
    const f32x4 a0 = *(const f32x4*)(s0);
    const f32x4 a1 = *(const f32x4*)(s0 + 4);
    const f32x4 b0 = *(const f32x4*)(s0 + DDIM);
    const f32x4 b1 = *(const f32x4*)(s0 + DDIM + 4);
#pragma unroll
    for (int j = 0; j < 4; ++j) {
      union { bf16_t h[2]; unsigned int u; } p;
      p.h[0] = (bf16_t)a0[j]; p.h[1] = (bf16_t)b0[j];
      T[cg * 8 + j][kp] = p.u;
      p.h[0] = (bf16_t)a1[j]; p.h[1] = (bf16_t)b1[j];
      T[cg * 8 + 4 + j][kp] = p.u;
    }
  }
  __syncthreads();
  {
    const int rn = t >> 2, q = t & 3;    // rn: out row 0..63, q: 16B chunk 0..3
    unsigned int r0[4], r1[4];
#pragma unroll
    for (int i = 0; i < 4; ++i) { r0[i] = T[rn][q * 4 + i]; r1[i] = T[rn][q * 4 + 16 + i]; }
    bf16_t* d = dst + (size_t)(n0 + rn) * DDIM + k0;
    const u32x4 v0 = { r0[0], r0[1], r0[2], r0[3] };
    const u32x4 v1 = { r1[0], r1[1], r1[2], r1[3] };
    *(u32x4*)(d + q * 8) = v0;        // 4 lanes -> 64B contiguous
    *(u32x4*)(d + q * 8 + 32) = v1;
  }
}

// ---------------- router: fp32 logits, softmax, top-2 (ties -> lowest idx) ----------------
__global__ void router_k(const float* __restrict__ x, const float* __restrict__ rw,
                         const float* __restrict__ bias, int* __restrict__ counts,
                         int* __restrict__ tsel, int* __restrict__ tpos,
                         float* __restrict__ tscore) {
  const int n = blockIdx.x;
  const int lane = threadIdx.x;  // 64
  float acc[8];
#pragma unroll
  for (int e = 0; e < 8; ++e) acc[e] = 0.f;
  for (int d = lane; d < DDIM; d += 64) {
    const float xv = x[n * DDIM + d];
    const f32x4 w0 = *(const f32x4*)(rw + d * 8);
    const f32x4 w1 = *(const f32x4*)(rw + d * 8 + 4);
#pragma unroll
    for (int e = 0; e < 4; ++e) { acc[e] += xv * w0[e]; acc[e + 4] += xv * w1[e]; }
  }
#pragma unroll
  for (int off = 32; off >= 1; off >>= 1)
#pragma unroll
    for (int e = 0; e < 8; ++e) acc[e] += __shfl_xor(acc[e], off, 64);

  if (lane == 0) {
    float mx = acc[0];
#pragma unroll
    for (int e = 1; e < 8; ++e) mx = fmaxf(mx, acc[e]);
    float p[8], s = 0.f;
#pragma unroll
    for (int e = 0; e < 8; ++e) { p[e] = __expf(acc[e] - mx); s += p[e]; }
    const float inv = 1.f / s;
    float sc[8], sb[8];
#pragma unroll
    for (int e = 0; e < 8; ++e) { sc[e] = p[e] * inv; sb[e] = sc[e] + bias[e]; }
    int i1 = 0;
#pragma unroll
    for (int e = 1; e < 8; ++e) if (sb[e] > sb[i1]) i1 = e;
    int i2 = (i1 == 0) ? 1 : 0;
#pragma unroll
    for (int e = 0; e < 8; ++e) if (e != i2 && e != i1 && sb[e] > sb[i2]) i2 = e;
    int pos = atomicAdd(&counts[i1], 1);
    tsel[n * 2 + 0] = i1; tpos[n * 2 + 0] = pos; tscore[n * 2 + 0] = sc[i1];
    pos = atomicAdd(&counts[i2], 1);
    tsel[n * 2 + 1] = i2; tpos[n * 2 + 1] = pos; tscore[n * 2 + 1] = sc[i2];
  }
}

// ---------------- scan: 64-padded per-expert slot bases + tile table ----------------
__global__ void scan_k(const int* __restrict__ counts, int* __restrict__ slot_base,
                       int* __restrict__ ntp, int* __restrict__ tile_e,
                       int* __restrict__ tile_m0) {
  if (threadIdx.x != 0) return;
  int pt = 0;
  for (int e = 0; e < 8; ++e) {
    slot_base[e] = pt * TM;
    const int nt = (counts[e] + TM - 1) / TM;
    for (int j = 0; j < nt; ++j) { tile_e[pt] = e; tile_m0[pt] = slot_base[e] + j * TM; ++pt; }
  }
  slot_base[8] = pt * TM;  // shared expert: 16 full tiles
  for (int j = 0; j < 16; ++j) { tile_e[pt] = 8; tile_m0[pt] = slot_base[8] + j * TM; ++pt; }
  ntp[0] = pt;  // <= 55
}

// ---------------- fill: scatter (token, score) into compacted slots ----------------
__global__ void fill_k(const int* __restrict__ tsel, const int* __restrict__ tpos,
                       const float* __restrict__ tscore, const int* __restrict__ slot_base,
                       int* __restrict__ list, float* __restrict__ wrow) {
  const int i = blockIdx.x * 256 + threadIdx.x;  // grid 12*256 = 3072
  if (i < 2048) {
    const int e = tsel[i];
    const int slot = slot_base[e] + tpos[i];
    list[slot] = i >> 1; wrow[slot] = tscore[i];
  } else {
    const int t = i - 2048;
    const int slot = slot_base[8] + t;
    list[slot] = t; wrow[slot] = 1.f;
  }
}

// ---------------- wave-private LDS-free grouped GEMM. MODE: 0=U  1=V+SwiGLU  2=O ----------------
// Each wave owns a 64x32 tile: A/B fragments loaded straight from global into VGPRs
// (per-lane 16B loads; K-offsets fold into 13-bit immediates on the fully unrolled loop).
// No __syncthreads, no LDS, no vmcnt(0) drains -> compiler pipelines loads across MFMAs.
template <int MODE>
__global__ __launch_bounds__(256, 2)
void gemmw_k(const bf16_t* __restrict__ xg, const bf16_t* __restrict__ wt,
             bf16_t* __restrict__ UG, float* __restrict__ oacc,
             const int* __restrict__ tile_e, const int* __restrict__ tile_m0,
             const int* __restrict__ ntp, const int* __restrict__ list,
             const float* __restrict__ wrow) {
  const int lane = threadIdx.x & 63;
  const int wid = blockIdx.x * 4 + (threadIdx.x >> 6);
  const int mt = wid >> 5;             // m-tile index (64 rows)
  if (mt >= ntp[0]) return;            // wave-uniform exit, no barriers anywhere
  const int nt = wid & 31;             // n-tile index (32 cols)
  const int e = tile_e[mt];
  const int slot0 = tile_m0[mt];
  const int n0 = nt * TNW;
  const int row = lane & 15, quad = lane >> 4;

  const bf16_t* aB[4];
#pragma unroll
  for (int mf = 0; mf < 4; ++mf) {
    const int slot = slot0 + mf * 16 + row;
    const int src = (MODE == 2) ? slot : list[slot];
    aB[mf] = ((MODE == 2) ? UG : xg) + (size_t)src * DDIM + quad * 8;
  }
  const bf16_t* bB[2];
#pragma unroll
  for (int nf = 0; nf < 2; ++nf)
    bB[nf] = wt + (size_t)e * MATN + (size_t)(n0 + nf * 16 + row) * DDIM + quad * 8;

  const f32x4 z = {0.f, 0.f, 0.f, 0.f};
  f32x4 acc[4][2];
#pragma unroll
  for (int a = 0; a < 4; ++a)
#pragma unroll
    for (int b = 0; b < 2; ++b) acc[a][b] = z;

#pragma unroll
  for (int k = 0; k < DDIM; k += 32) {
    bf16x8 af[4], fb[2];
#pragma unroll
    for (int mf = 0; mf < 4; ++mf) af[mf] = *(const bf16x8*)(aB[mf] + k);
#pragma unroll
    for (int nf = 0; nf < 2; ++nf) fb[nf] = *(const bf16x8*)(bB[nf] + k);
#pragma unroll
    for (int nf = 0; nf < 2; ++nf)
#pragma unroll
      for (int mf = 0; mf < 4; ++mf)
        acc[mf][nf] = __builtin_amdgcn_mfma_f32_16x16x32_bf16(af[mf], fb[nf], acc[mf][nf], 0, 0, 0);
  }

  // C/D layout: col=lane&15, row=quad*4+reg (m89/m91). Pads: wrow=0 -> contribute 0.
  const int colb = n0 + row;
#pragma unroll
  for (int mf = 0; mf < 4; ++mf) {
#pragma unroll
    for (int rg = 0; rg < 4; ++rg) {
      const int r = mf * 16 + quad * 4 + rg;
      const int slot = slot0 + r;
      if (MODE == 0) {
        bf16_t* gp = UG + (size_t)slot * DDIM + colb;
#pragma unroll
        for (int nf = 0; nf < 2; ++nf) gp[nf * 16] = (bf16_t)acc[mf][nf][rg];
      } else if (MODE == 1) {
        bf16_t* gp = UG + (size_t)slot * DDIM + colb;
#pragma unroll
        for (int nf = 0; nf < 2; ++nf) {
          const float u = (float)gp[nf * 16];                          // U = X W1^T
          const float g = (u / (1.f + __expf(-u))) * acc[mf][nf][rg];  // silu(U)*V
          gp[nf * 16] = (bf16_t)g;                                     // G in place
        }
      } else {
        const float w = wrow[slot];
        if (w != 0.f) {
          const int tok = list[slot];
          float* dst = oacc + (size_t)tok * DDIM + colb;
#pragma unroll
          for (int nf = 0; nf < 2; ++nf)
            atomicAdd(dst + nf * 16, w * acc[mf][nf][rg]);
        }
      }
    }
  }
}

extern "C" void kernel_launch(void* const* d_in, const int* in_sizes, int n_in,
                              void* d_out, int out_size, void* d_ws, size_t ws_size,
                              hipStream_t stream) {
  (void)in_sizes; (void)n_in; (void)out_size; (void)ws_size;
  const float* x   = (const float*)d_in[0];
  const float* rw  = (const float*)d_in[1];
  const float* eb  = (const float*)d_in[2];
  const float* w1  = (const float*)d_in[3];
  const float* w2  = (const float*)d_in[4];
  const float* w3  = (const float*)d_in[5];
  const float* sw1 = (const float*)d_in[6];
  const float* sw2 = (const float*)d_in[7];
  const float* sw3 = (const float*)d_in[8];
  float* out = (float*)d_out;   // fp32; accumulate in place

  char* ws = (char*)d_ws;
  bf16_t* wt = (bf16_t*)(ws);                 // 9 * 2 MiB, reused for W1^T/W3^T/W2^T
  bf16_t* xb = (bf16_t*)(ws + 18874368);      // [1024][1024] bf16
  bf16_t* G  = (bf16_t*)(ws + 20971520);      // [4096][1024] bf16: U then G in place
  int*  meta = (int*)(ws + 29360128);
  int*   counts    = meta;                    // 16
  int*   slot_base = meta + 16;               // 16
  int*   ntp       = meta + 32;               // 8
  int*   tile_e    = meta + 40;               // 64
  int*   tile_m0   = meta + 104;              // 64
  int*   tsel      = meta + 168;              // 2048
  int*   tpos      = meta + 2216;             // 2048
  int*   list      = meta + 4264;             // 4096
  float* tscore    = (float*)(meta + 8360);   // 2048
  float* wrow      = (float*)(meta + 10408);  // 4096

  hipMemsetAsync(out, 0, (size_t)NTOK * DDIM * sizeof(float), stream);
  prep_k<<<512, 256, 0, stream>>>(x, xb, counts, list, wrow);
  router_k<<<NTOK, 64, 0, stream>>>(x, rw, eb, counts, tsel, tpos, tscore);
  scan_k<<<1, 64, 0, stream>>>(counts, slot_base, ntp, tile_e, tile_m0);
  fill_k<<<12, 256, 0, stream>>>(tsel, tpos, tscore, slot_base, list, wrow);

  // max tiles = 39 routed + 16 shared = 55 -> 55*32 waves / 4 = 440 blocks
  // Stage 1: U = X W1^T
  transpose_k<<<dim3(16, 16, 9), 256, 0, stream>>>(w1, sw1, wt);
  gemmw_k<0><<<440, 256, 0, stream>>>(xb, wt, G, out, tile_e, tile_m0, ntp, list, wrow);
  // Stage 2: V = X W3^T, G = silu(U) * V (in place)
  transpose_k<<<dim3(16, 16, 9), 256, 0, stream>>>(w3, sw3, wt);
  gemmw_k<1><<<440, 256, 0, stream>>>(xb, wt, G, out, tile_e, tile_m0, ntp, list, wrow);
  // Stage 3: out[tok] += wrow * (G W2^T)
  transpose_k<<<dim3(16, 16, 9), 256, 0, stream>>>(w2, sw2, wt);
  gemmw_k<2><<<440, 256, 0, stream>>>(G, wt, G, out, tile_e, tile_m0, ntp, list, wrow);
}

// Round 6
// 247.075 us; speedup vs baseline: 1.4229x; 1.4229x over previous
//
#include <hip/hip_runtime.h>
#include <hip/hip_bf16.h>

typedef __bf16 bf16_t;
typedef __bf16 bf16x8 __attribute__((ext_vector_type(8)));
typedef float  f32x4  __attribute__((ext_vector_type(4)));
typedef unsigned int u32x4 __attribute__((ext_vector_type(4)));

#define DDIM 1024
#define NTOK 1024
#define MATN (1024 * 1024)
#define BK 64

// raw barrier / partial vm-wait: __syncthreads would emit s_waitcnt vmcnt(0)
// and drain the prefetch (the m97 ~20% stall). m139-style raw s_barrier is
// correct; "memory" clobber pins compiler ordering of LDS/global ops.
#define BAR()   asm volatile("s_barrier" ::: "memory")
#define WVM(n)  asm volatile("s_waitcnt vmcnt(" #n ")" ::: "memory")

__device__ __forceinline__ void load16(const bf16_t* g, bf16_t* l) {
  __builtin_amdgcn_global_load_lds(
      (__attribute__((address_space(1))) void*)(g),
      (__attribute__((address_space(3))) void*)(l), 16, 0, 0);
}

// swizzled fragment offset: elem (row 0..63, k-group g=kk/8) lives at
// row*64 + ((g ^ (row&7))*8)   [gather side permuted to match]
__device__ __forceinline__ int sw_off(int row, int kk) {
  return row * BK + (((kk >> 3) ^ (row & 7)) << 3);
}

// ---------------- prep: x->bf16, zero out, init counters/pads ----------------
__global__ void prep_k(const float* __restrict__ x, bf16_t* __restrict__ xb,
                       float* __restrict__ out, int* __restrict__ counts,
                       int* __restrict__ list, float* __restrict__ wrow) {
  const int i = blockIdx.x * 256 + threadIdx.x;  // 512 blocks
  const int j = i * 8;
  const f32x4 a = *(const f32x4*)(x + j);
  const f32x4 b = *(const f32x4*)(x + j + 4);
  bf16x8 v;
#pragma unroll
  for (int t = 0; t < 4; ++t) { v[t] = (bf16_t)a[t]; v[t + 4] = (bf16_t)b[t]; }
  *(bf16x8*)(xb + j) = v;
  const f32x4 z = {0.f, 0.f, 0.f, 0.f};
  *(f32x4*)(out + j) = z; *(f32x4*)(out + j + 4) = z;
  if (i < 16) counts[i] = 0;
  if (i < 4096) { list[i] = 0; wrow[i] = 0.f; }
}

// ---------------- weight transpose+convert: two weight kinds per dispatch ----------------
__global__ void transpose2_k(const float* __restrict__ a8, const float* __restrict__ aS,
                             bf16_t* __restrict__ da,
                             const float* __restrict__ b8, const float* __restrict__ bS,
                             bf16_t* __restrict__ db) {
  const int z = blockIdx.z, kind = z / 9, e = z % 9;
  const float* src = kind ? ((e < 8) ? b8 + (size_t)e * MATN : bS)
                          : ((e < 8) ? a8 + (size_t)e * MATN : aS);
  bf16_t* dst = (kind ? db : da) + (size_t)e * MATN;

  __shared__ unsigned int T[64][33];
  const int t = threadIdx.x;
  const int k0 = blockIdx.y * 64, n0 = blockIdx.x * 64;
  {
    const int kp = t >> 3, cg = t & 7;
    const float* s0 = src + (size_t)(k0 + 2 * kp) * DDIM + n0 + cg * 8;
    const f32x4 a0 = *(const f32x4*)(s0);
    const f32x4 a1 = *(const f32x4*)(s0 + 4);
    const f32x4 b0 = *(const f32x4*)(s0 + DDIM);
    const f32x4 b1 = *(const f32x4*)(s0 + DDIM + 4);
#pragma unroll
    for (int j = 0; j < 4; ++j) {
      union { bf16_t h[2]; unsigned int u; } p;
      p.h[0] = (bf16_t)a0[j]; p.h[1] = (bf16_t)b0[j];
      T[cg * 8 + j][kp] = p.u;
      p.h[0] = (bf16_t)a1[j]; p.h[1] = (bf16_t)b1[j];
      T[cg * 8 + 4 + j][kp] = p.u;
    }
  }
  __syncthreads();
  {
    const int rn = t >> 2, q = t & 3;
    unsigned int r0[4], r1[4];
#pragma unroll
    for (int i = 0; i < 4; ++i) { r0[i] = T[rn][q * 4 + i]; r1[i] = T[rn][q * 4 + 16 + i]; }
    bf16_t* d = dst + (size_t)(n0 + rn) * DDIM + k0;
    const u32x4 v0 = { r0[0], r0[1], r0[2], r0[3] };
    const u32x4 v1 = { r1[0], r1[1], r1[2], r1[3] };
    *(u32x4*)(d + q * 8) = v0;
    *(u32x4*)(d + q * 8 + 32) = v1;
  }
}

// ---------------- router ----------------
__global__ void router_k(const float* __restrict__ x, const float* __restrict__ rw,
                         const float* __restrict__ bias, int* __restrict__ counts,
                         int* __restrict__ tsel, int* __restrict__ tpos,
                         float* __restrict__ tscore) {
  const int n = blockIdx.x;
  const int lane = threadIdx.x;
  float acc[8];
#pragma unroll
  for (int e = 0; e < 8; ++e) acc[e] = 0.f;
  for (int d = lane; d < DDIM; d += 64) {
    const float xv = x[n * DDIM + d];
    const f32x4 w0 = *(const f32x4*)(rw + d * 8);
    const f32x4 w1 = *(const f32x4*)(rw + d * 8 + 4);
#pragma unroll
    for (int e = 0; e < 4; ++e) { acc[e] += xv * w0[e]; acc[e + 4] += xv * w1[e]; }
  }
#pragma unroll
  for (int off = 32; off >= 1; off >>= 1)
#pragma unroll
    for (int e = 0; e < 8; ++e) acc[e] += __shfl_xor(acc[e], off, 64);
  if (lane == 0) {
    float mx = acc[0];
#pragma unroll
    for (int e = 1; e < 8; ++e) mx = fmaxf(mx, acc[e]);
    float p[8], s = 0.f;
#pragma unroll
    for (int e = 0; e < 8; ++e) { p[e] = __expf(acc[e] - mx); s += p[e]; }
    const float inv = 1.f / s;
    float sc[8], sb[8];
#pragma unroll
    for (int e = 0; e < 8; ++e) { sc[e] = p[e] * inv; sb[e] = sc[e] + bias[e]; }
    int i1 = 0;
#pragma unroll
    for (int e = 1; e < 8; ++e) if (sb[e] > sb[i1]) i1 = e;   // ties -> lowest idx
    int i2 = (i1 == 0) ? 1 : 0;
#pragma unroll
    for (int e = 0; e < 8; ++e) if (e != i2 && e != i1 && sb[e] > sb[i2]) i2 = e;
    int pos = atomicAdd(&counts[i1], 1);
    tsel[n * 2 + 0] = i1; tpos[n * 2 + 0] = pos; tscore[n * 2 + 0] = sc[i1];
    pos = atomicAdd(&counts[i2], 1);
    tsel[n * 2 + 1] = i2; tpos[n * 2 + 1] = pos; tscore[n * 2 + 1] = sc[i2];
  }
}

// ---------------- pack: scan (thread 0) + fill, one dispatch ----------------
__global__ void pack_k(const int* __restrict__ counts, const int* __restrict__ tsel,
                       const int* __restrict__ tpos, const float* __restrict__ tscore,
                       int* __restrict__ ntp, int* __restrict__ tile_e,
                       int* __restrict__ tile_m0, int* __restrict__ list,
                       float* __restrict__ wrow) {
  __shared__ int sb[9];
  if (threadIdx.x == 0) {
    int pt = 0;
    for (int e = 0; e < 8; ++e) {
      sb[e] = pt * 64;
      const int nt = (counts[e] + 63) / 64;
      for (int j = 0; j < nt; ++j) { tile_e[pt] = e; tile_m0[pt] = sb[e] + j * 64; ++pt; }
    }
    sb[8] = pt * 64;
    for (int j = 0; j < 16; ++j) { tile_e[pt] = 8; tile_m0[pt] = sb[8] + j * 64; ++pt; }
    ntp[0] = pt;  // <= 56
  }
  __syncthreads();
  for (int i = threadIdx.x; i < 3072; i += 1024) {
    if (i < 2048) {
      const int e = tsel[i];
      const int slot = sb[e] + tpos[i];
      list[slot] = i >> 1; wrow[slot] = tscore[i];
    } else {
      const int t = i - 2048;
      const int slot = sb[8] + t;
      list[slot] = t; wrow[slot] = 1.f;
    }
  }
}

// ---------------- fused dual-B GEMM: G = silu(X W1^T) * (X W3^T) ----------------
// 64x64 tile, double-buffered LDS, raw-barrier pipeline, swizzled layout.
__global__ __launch_bounds__(256, 3)
void gemm12_k(const bf16_t* __restrict__ xb, const bf16_t* __restrict__ wt1,
              const bf16_t* __restrict__ wt3, bf16_t* __restrict__ G,
              const int* __restrict__ tile_e, const int* __restrict__ tile_m0,
              const int* __restrict__ ntp, const int* __restrict__ list) {
  const int ti = blockIdx.y;
  if (ti >= ntp[0]) return;
  const int e = tile_e[ti], slot0 = tile_m0[ti];
  const int n0 = blockIdx.x * 64;

  __shared__ __align__(16) bf16_t sA[2][64 * BK];
  __shared__ __align__(16) bf16_t sB1[2][64 * BK];
  __shared__ __align__(16) bf16_t sB3[2][64 * BK];

  const int lane = threadIdx.x & 63, wave = threadIdx.x >> 6;
  const int wm = wave & 1, wn = wave >> 1;
  const int srr = lane >> 3;
  const int scol = ((lane & 7) ^ srr) * 8;   // swizzled gather column

  const bf16_t *aS[2], *b1S[2], *b3S[2];
#pragma unroll
  for (int i = 0; i < 2; ++i) {
    const int c = wave * 2 + i;
    const int r = c * 8 + srr;
    aS[i] = xb + (size_t)list[slot0 + r] * DDIM + scol;
    const size_t wb = (size_t)e * MATN + (size_t)(n0 + r) * DDIM + scol;
    b1S[i] = wt1 + wb; b3S[i] = wt3 + wb;
  }

  const f32x4 z = {0.f, 0.f, 0.f, 0.f};
  f32x4 aU[2][2], aV[2][2];
#pragma unroll
  for (int a = 0; a < 2; ++a)
#pragma unroll
    for (int b = 0; b < 2; ++b) { aU[a][b] = z; aV[a][b] = z; }

#define ISSUE12(j, b)                                            \
  _Pragma("unroll") for (int i = 0; i < 2; ++i) {                \
    const int c = wave * 2 + i;                                  \
    load16(aS[i] + (j) * BK, &sA[b][c * 512]);                   \
    load16(b1S[i] + (j) * BK, &sB1[b][c * 512]);                 \
    load16(b3S[i] + (j) * BK, &sB3[b][c * 512]);                 \
  }

#define COMPUTE12(b)                                                          \
  _Pragma("unroll") for (int ks = 0; ks < 2; ++ks) {                          \
    const int kk = ks * 32 + ((lane >> 4) * 8);                               \
    bf16x8 af[2], f1[2], f3[2];                                               \
    _Pragma("unroll") for (int mf = 0; mf < 2; ++mf)                          \
      af[mf] = *(const bf16x8*)&sA[b][sw_off(wm * 32 + mf * 16 + (lane & 15), kk)]; \
    _Pragma("unroll") for (int nf = 0; nf < 2; ++nf) {                        \
      const int ro = sw_off(wn * 32 + nf * 16 + (lane & 15), kk);             \
      f1[nf] = *(const bf16x8*)&sB1[b][ro];                                   \
      f3[nf] = *(const bf16x8*)&sB3[b][ro];                                   \
    }                                                                         \
    _Pragma("unroll") for (int nf = 0; nf < 2; ++nf)                          \
      _Pragma("unroll") for (int mf = 0; mf < 2; ++mf) {                      \
        aU[mf][nf] = __builtin_amdgcn_mfma_f32_16x16x32_bf16(af[mf], f1[nf], aU[mf][nf], 0, 0, 0); \
        aV[mf][nf] = __builtin_amdgcn_mfma_f32_16x16x32_bf16(af[mf], f3[nf], aV[mf][nf], 0, 0, 0); \
      }                                                                       \
  }

  ISSUE12(0, 0);
#pragma unroll
  for (int j = 0; j < 15; ++j) {
    ISSUE12(j + 1, (j + 1) & 1);
    WVM(6); BAR();
    COMPUTE12(j & 1);
    BAR();
  }
  WVM(0); BAR();
  COMPUTE12(1);

  // epilogue: G = silu(U)*V.  C/D: col=lane&15, row=quad*4+reg (m89/m91)
  const int colb = n0 + wn * 32 + (lane & 15);
#pragma unroll
  for (int mf = 0; mf < 2; ++mf)
#pragma unroll
    for (int rg = 0; rg < 4; ++rg) {
      const int row = wm * 32 + mf * 16 + ((lane >> 4) * 4) + rg;
      bf16_t* gp = G + (size_t)(slot0 + row) * DDIM + colb;
#pragma unroll
      for (int nf = 0; nf < 2; ++nf) {
        const float u = aU[mf][nf][rg];
        gp[nf * 16] = (bf16_t)((u / (1.f + __expf(-u))) * aV[mf][nf][rg]);
      }
    }
#undef ISSUE12
#undef COMPUTE12
}

// ---------------- single-B GEMM (dbuf+swizzle). MODE: 0=U 1=V+SwiGLU 2=out ----------------
template <int MODE>
__global__ __launch_bounds__(256, 4)
void gemmS_k(const bf16_t* __restrict__ Asrc, const bf16_t* __restrict__ wt,
             bf16_t* __restrict__ UG, float* __restrict__ oacc,
             const int* __restrict__ tile_e, const int* __restrict__ tile_m0,
             const int* __restrict__ ntp, const int* __restrict__ list,
             const float* __restrict__ wrow) {
  const int ti = blockIdx.y;
  if (ti >= ntp[0]) return;
  const int e = tile_e[ti], slot0 = tile_m0[ti];
  const int n0 = blockIdx.x * 64;

  __shared__ __align__(16) bf16_t sA[2][64 * BK];
  __shared__ __align__(16) bf16_t sB[2][64 * BK];

  const int lane = threadIdx.x & 63, wave = threadIdx.x >> 6;
  const int wm = wave & 1, wn = wave >> 1;
  const int srr = lane >> 3;
  const int scol = ((lane & 7) ^ srr) * 8;

  const bf16_t *aS[2], *bS[2];
#pragma unroll
  for (int i = 0; i < 2; ++i) {
    const int c = wave * 2 + i;
    const int r = c * 8 + srr;
    const int slot = slot0 + r;
    aS[i] = Asrc + (size_t)((MODE == 2) ? slot : list[slot]) * DDIM + scol;
    bS[i] = wt + (size_t)e * MATN + (size_t)(n0 + r) * DDIM + scol;
  }

  const f32x4 z = {0.f, 0.f, 0.f, 0.f};
  f32x4 acc[2][2];
#pragma unroll
  for (int a = 0; a < 2; ++a)
#pragma unroll
    for (int b = 0; b < 2; ++b) acc[a][b] = z;

#define ISSUES(j, b)                                   \
  _Pragma("unroll") for (int i = 0; i < 2; ++i) {      \
    const int c = wave * 2 + i;                        \
    load16(aS[i] + (j) * BK, &sA[b][c * 512]);         \
    load16(bS[i] + (j) * BK, &sB[b][c * 512]);         \
  }

#define COMPUTES(b)                                                           \
  _Pragma("unroll") for (int ks = 0; ks < 2; ++ks) {                          \
    const int kk = ks * 32 + ((lane >> 4) * 8);                               \
    bf16x8 af[2], fb[2];                                                      \
    _Pragma("unroll") for (int mf = 0; mf < 2; ++mf)                          \
      af[mf] = *(const bf16x8*)&sA[b][sw_off(wm * 32 + mf * 16 + (lane & 15), kk)]; \
    _Pragma("unroll") for (int nf = 0; nf < 2; ++nf)                          \
      fb[nf] = *(const bf16x8*)&sB[b][sw_off(wn * 32 + nf * 16 + (lane & 15), kk)]; \
    _Pragma("unroll") for (int nf = 0; nf < 2; ++nf)                          \
      _Pragma("unroll") for (int mf = 0; mf < 2; ++mf)                        \
        acc[mf][nf] = __builtin_amdgcn_mfma_f32_16x16x32_bf16(af[mf], fb[nf], acc[mf][nf], 0, 0, 0); \
  }

  ISSUES(0, 0);
#pragma unroll
  for (int j = 0; j < 15; ++j) {
    ISSUES(j + 1, (j + 1) & 1);
    WVM(4); BAR();
    COMPUTES(j & 1);
    BAR();
  }
  WVM(0); BAR();
  COMPUTES(1);

  const int colb = n0 + wn * 32 + (lane & 15);
#pragma unroll
  for (int mf = 0; mf < 2; ++mf)
#pragma unroll
    for (int rg = 0; rg < 4; ++rg) {
      const int row = wm * 32 + mf * 16 + ((lane >> 4) * 4) + rg;
      const int slot = slot0 + row;
      if (MODE == 0) {
        bf16_t* gp = UG + (size_t)slot * DDIM + colb;
#pragma unroll
        for (int nf = 0; nf < 2; ++nf) gp[nf * 16] = (bf16_t)acc[mf][nf][rg];
      } else if (MODE == 1) {
        bf16_t* gp = UG + (size_t)slot * DDIM + colb;
#pragma unroll
        for (int nf = 0; nf < 2; ++nf) {
          const float u = (float)gp[nf * 16];
          gp[nf * 16] = (bf16_t)((u / (1.f + __expf(-u))) * acc[mf][nf][rg]);
        }
      } else {
        const float w = wrow[slot];
        if (w != 0.f) {
          float* dst = oacc + (size_t)list[slot] * DDIM + colb;
#pragma unroll
          for (int nf = 0; nf < 2; ++nf)
            atomicAdd(dst + nf * 16, w * acc[mf][nf][rg]);
        }
      }
    }
#undef ISSUES
#undef COMPUTES
}

extern "C" void kernel_launch(void* const* d_in, const int* in_sizes, int n_in,
                              void* d_out, int out_size, void* d_ws, size_t ws_size,
                              hipStream_t stream) {
  (void)in_sizes; (void)n_in; (void)out_size;
  const float* x   = (const float*)d_in[0];
  const float* rw  = (const float*)d_in[1];
  const float* eb  = (const float*)d_in[2];
  const float* w1  = (const float*)d_in[3];
  const float* w2  = (const float*)d_in[4];
  const float* w3  = (const float*)d_in[5];
  const float* sw1 = (const float*)d_in[6];
  const float* sw2 = (const float*)d_in[7];
  const float* sw3 = (const float*)d_in[8];
  float* out = (float*)d_out;

  char* ws = (char*)d_ws;
  const size_t WT = 18874368;  // 9 * 2 MiB bf16
  const bool fused = (ws_size >= 2 * WT + 2097152 + 8388608 + 65536);

  bf16_t *wtA, *wtB, *xb, *G; int* meta;
  if (fused) {
    wtA = (bf16_t*)(ws);            // w1^T, later w2^T
    wtB = (bf16_t*)(ws + WT);       // w3^T
    xb  = (bf16_t*)(ws + 2 * WT);
    G   = (bf16_t*)(ws + 2 * WT + 2097152);
    meta = (int*)(ws + 2 * WT + 2097152 + 8388608);
  } else {
    wtA = wtB = (bf16_t*)(ws);      // sequential reuse
    xb  = (bf16_t*)(ws + WT);
    G   = (bf16_t*)(ws + WT + 2097152);
    meta = (int*)(ws + WT + 2097152 + 8388608);
  }
  int*   counts  = meta;
  int*   ntp     = meta + 32;
  int*   tile_e  = meta + 40;
  int*   tile_m0 = meta + 104;
  int*   tsel    = meta + 168;
  int*   tpos    = meta + 2216;
  int*   list    = meta + 4264;
  float* tscore  = (float*)(meta + 8360);
  float* wrow    = (float*)(meta + 10408);

  prep_k<<<512, 256, 0, stream>>>(x, xb, out, counts, list, wrow);
  router_k<<<NTOK, 64, 0, stream>>>(x, rw, eb, counts, tsel, tpos, tscore);
  pack_k<<<1, 1024, 0, stream>>>(counts, tsel, tpos, tscore, ntp, tile_e, tile_m0, list, wrow);

  if (fused) {
    transpose2_k<<<dim3(16, 16, 18), 256, 0, stream>>>(w1, sw1, wtA, w3, sw3, wtB);
    gemm12_k<<<dim3(16, 56), 256, 0, stream>>>(xb, wtA, wtB, G, tile_e, tile_m0, ntp, list);
    transpose2_k<<<dim3(16, 16, 9), 256, 0, stream>>>(w2, sw2, wtA, w2, sw2, wtA);
    gemmS_k<2><<<dim3(16, 56), 256, 0, stream>>>(G, wtA, G, out, tile_e, tile_m0, ntp, list, wrow);
  } else {
    transpose2_k<<<dim3(16, 16, 9), 256, 0, stream>>>(w1, sw1, wtA, w1, sw1, wtA);
    gemmS_k<0><<<dim3(16, 56), 256, 0, stream>>>(xb, wtA, G, out, tile_e, tile_m0, ntp, list, wrow);
    transpose2_k<<<dim3(16, 16, 9), 256, 0, stream>>>(w3, sw3, wtA, w3, sw3, wtA);
    gemmS_k<1><<<dim3(16, 56), 256, 0, stream>>>(xb, wtA, G, out, tile_e, tile_m0, ntp, list, wrow);
    transpose2_k<<<dim3(16, 16, 9), 256, 0, stream>>>(w2, sw2, wtA, w2, sw2, wtA);
    gemmS_k<2><<<dim3(16, 56), 256, 0, stream>>>(G, wtA, G, out, tile_e, tile_m0, ntp, list, wrow);
  }
}